// Round 1
// baseline (348.948 us; speedup 1.0000x reference)
//
#include <hip/hip_runtime.h>

typedef unsigned short u16;
typedef __attribute__((ext_vector_type(8))) unsigned short ushort8;
typedef __attribute__((ext_vector_type(8))) __bf16 bf16x8;
typedef __attribute__((ext_vector_type(4))) float f32x4;

#define T_SEQ 2048
#define WINDOW 1024

static __device__ __forceinline__ u16 f2bf(float f) {
    unsigned int u = __float_as_uint(f);
    u += 0x7fffu + ((u >> 16) & 1u);
    return (u16)(u >> 16);
}
static __device__ __forceinline__ float bf2f(u16 h) {
    return __uint_as_float(((unsigned int)h) << 16);
}
static __device__ __forceinline__ bf16x8 ld_bf8(const u16* p) {
    return __builtin_bit_cast(bf16x8, *(const ushort8*)p);
}

// ---------------- QKV GEMM: C[4096 x 3072] = x[4096 x 2048] @ [Wq|Wk|Wv] ----------------
// Epilogue scatters to Q (B,H,T,D), K/V (B,Hkv,T,D) bf16.
__global__ __launch_bounds__(256)
void qkv_gemm(const float* __restrict__ x,
              const float* __restrict__ Wq, const float* __restrict__ Wk,
              const float* __restrict__ Wv,
              u16* __restrict__ Qb, u16* __restrict__ Kb, u16* __restrict__ Vb)
{
    const int K = 2048;
    __shared__ __align__(16) u16 Al[128][40];
    __shared__ __align__(16) u16 Bl[128][40];
    const int tid = threadIdx.x;
    const int lane = tid & 63;
    const int w = tid >> 6;
    const int wm = w >> 1, wn = w & 1;
    const int m0 = blockIdx.x * 128;
    const int n0g = blockIdx.y * 128;

    const float* Bsrc; int ldb; int nb;
    if (n0g < 2048)      { Bsrc = Wq; ldb = 2048; nb = n0g; }
    else if (n0g < 2560) { Bsrc = Wk; ldb = 512;  nb = n0g - 2048; }
    else                 { Bsrc = Wv; ldb = 512;  nb = n0g - 2560; }

    f32x4 acc[4][4] = {};

    const int ar = tid >> 1;
    const int ak = (tid & 1) * 16;
    const int bn = tid & 127;
    const int bk0 = (tid >> 7) * 16;

    for (int kb = 0; kb < K; kb += 32) {
        // stage A (fp32 -> bf16)
        {
            const float* ag = x + (size_t)(m0 + ar) * K + kb + ak;
            float4 v0 = *(const float4*)(ag + 0);
            float4 v1 = *(const float4*)(ag + 4);
            float4 v2 = *(const float4*)(ag + 8);
            float4 v3 = *(const float4*)(ag + 12);
            ushort8 s0 = { f2bf(v0.x), f2bf(v0.y), f2bf(v0.z), f2bf(v0.w),
                           f2bf(v1.x), f2bf(v1.y), f2bf(v1.z), f2bf(v1.w) };
            ushort8 s1 = { f2bf(v2.x), f2bf(v2.y), f2bf(v2.z), f2bf(v2.w),
                           f2bf(v3.x), f2bf(v3.y), f2bf(v3.z), f2bf(v3.w) };
            *(ushort8*)&Al[ar][ak]     = s0;
            *(ushort8*)&Al[ar][ak + 8] = s1;
        }
        // stage B transposed: Bl[n][k]
        {
            const float* bg = Bsrc + (size_t)(kb + bk0) * ldb + nb + bn;
            #pragma unroll
            for (int i = 0; i < 16; ++i) {
                Bl[bn][bk0 + i] = f2bf(bg[(size_t)i * ldb]);
            }
        }
        __syncthreads();

        bf16x8 af[4], bfr[4];
        #pragma unroll
        for (int m = 0; m < 4; ++m)
            af[m] = ld_bf8(&Al[wm * 64 + m * 16 + (lane & 15)][(lane >> 4) * 8]);
        #pragma unroll
        for (int n = 0; n < 4; ++n)
            bfr[n] = ld_bf8(&Bl[wn * 64 + n * 16 + (lane & 15)][(lane >> 4) * 8]);
        #pragma unroll
        for (int m = 0; m < 4; ++m)
            #pragma unroll
            for (int n = 0; n < 4; ++n)
                acc[m][n] = __builtin_amdgcn_mfma_f32_16x16x32_bf16(af[m], bfr[n], acc[m][n], 0, 0, 0);
        __syncthreads();
    }

    const int r0 = (lane >> 4) * 4;
    const int c0 = lane & 15;
    #pragma unroll
    for (int m = 0; m < 4; ++m) {
        #pragma unroll
        for (int n = 0; n < 4; ++n) {
            #pragma unroll
            for (int r = 0; r < 4; ++r) {
                int row = m0 + wm * 64 + m * 16 + r0 + r;
                int col = n0g + wn * 64 + n * 16 + c0;
                float v = acc[m][n][r];
                int b = row >> 11, t = row & 2047;
                if (col < 2048) {
                    int h = col >> 6, d = col & 63;
                    Qb[(((size_t)b * 32 + h) * 2048 + t) * 64 + d] = f2bf(v);
                } else if (col < 2560) {
                    int c2 = col - 2048; int hk = c2 >> 6, d = c2 & 63;
                    Kb[(((size_t)b * 8 + hk) * 2048 + t) * 64 + d] = f2bf(v);
                } else {
                    int c2 = col - 2560; int hk = c2 >> 6, d = c2 & 63;
                    Vb[(((size_t)b * 8 + hk) * 2048 + t) * 64 + d] = f2bf(v);
                }
            }
        }
    }
}

// ---------------- RoPE in-place on Q and K ----------------
__global__ __launch_bounds__(256)
void rope_kernel(u16* __restrict__ Qb, u16* __restrict__ Kb)
{
    const int QP = 2 * 32 * 2048 * 32;   // 4,194,304 pairs
    const int KP = 2 * 8 * 2048 * 32;    // 1,048,576 pairs
    int idx = blockIdx.x * 256 + threadIdx.x;
    if (idx >= QP + KP) return;
    u16* buf; int p;
    if (idx < QP) { buf = Qb; p = idx; } else { buf = Kb; p = idx - QP; }
    int dp = p & 31;
    int t = (p >> 5) & 2047;
    int bh = p >> 16;
    size_t base = ((size_t)bh * 2048 + t) * 64 + dp;
    float x1 = bf2f(buf[base]);
    float x2 = bf2f(buf[base + 32]);
    float inv_freq = __expf(-dp * 0.28782313662425574f); // ln(10000)/32
    float ang = (float)t * inv_freq;
    float s, c;
    sincosf(ang, &s, &c);
    buf[base]      = f2bf(x1 * c - x2 * s);
    buf[base + 32] = f2bf(x2 * c + x1 * s);
}

// ---------------- Flash attention with sliding window ----------------
__global__ __launch_bounds__(256)
void attn_kernel(const u16* __restrict__ Qb, const u16* __restrict__ Kb,
                 const u16* __restrict__ Vb, u16* __restrict__ AO)
{
    __shared__ __align__(16) u16 Kl[64][72];
    __shared__ __align__(16) u16 Vl[64][72];   // transposed: Vl[d][j]
    __shared__ __align__(16) u16 Pl[4][16][72];

    const int tid = threadIdx.x;
    const int lane = tid & 63;
    const int w = tid >> 6;
    const int q0 = blockIdx.x * 64;
    const int bh = blockIdx.y;           // b*32 + h
    const int b = bh >> 5, h = bh & 31;
    const int hk = h >> 2;               // REPEATS = 4
    const size_t qbase  = (size_t)bh * 2048 * 64;
    const size_t kvbase = ((size_t)b * 8 + hk) * 2048 * 64;

    // Q fragments (rows q0 + w*16 + (lane&15), k = d)
    bf16x8 qf0, qf1;
    {
        const u16* qp = Qb + qbase + (size_t)(q0 + w * 16 + (lane & 15)) * 64 + ((lane >> 4) * 8);
        qf0 = ld_bf8(qp);
        qf1 = ld_bf8(qp + 32);
    }

    float mrun[4], lrun[4];
    f32x4 o[4] = {};
    #pragma unroll
    for (int r = 0; r < 4; ++r) { mrun[r] = -1e30f; lrun[r] = 0.f; }

    int kbeg = q0 - (WINDOW - 1);
    if (kbeg < 0) kbeg = 0;
    kbeg &= ~63;
    const float scale = 0.125f;  // 1/sqrt(64)

    const int wrow_min = q0 + w * 16;
    const int wrow_max = wrow_min + 15;

    for (int k0 = kbeg; k0 < q0 + 64; k0 += 64) {
        // stage K tile and V tile (transposed)
        {
            int j = tid >> 2;
            int d0 = (tid & 3) * 16;
            const u16* kg = Kb + kvbase + (size_t)(k0 + j) * 64 + d0;
            *(ushort8*)&Kl[j][d0]     = *(const ushort8*)kg;
            *(ushort8*)&Kl[j][d0 + 8] = *(const ushort8*)(kg + 8);
            const u16* vg = Vb + kvbase + (size_t)(k0 + j) * 64 + d0;
            #pragma unroll
            for (int i = 0; i < 16; ++i) Vl[d0 + i][j] = vg[i];
        }
        __syncthreads();

        bool active = (k0 <= wrow_max) && (k0 + 63 >= wrow_min - (WINDOW - 1));
        if (active) {
            // S = Q K^T  (16 rows x 64 keys per wave)
            f32x4 s[4];
            #pragma unroll
            for (int nf = 0; nf < 4; ++nf) {
                bf16x8 kb0 = ld_bf8(&Kl[nf * 16 + (lane & 15)][(lane >> 4) * 8]);
                bf16x8 kb1 = ld_bf8(&Kl[nf * 16 + (lane & 15)][32 + (lane >> 4) * 8]);
                f32x4 a = {};
                a = __builtin_amdgcn_mfma_f32_16x16x32_bf16(qf0, kb0, a, 0, 0, 0);
                a = __builtin_amdgcn_mfma_f32_16x16x32_bf16(qf1, kb1, a, 0, 0, 0);
                s[nf] = a;
            }
            // mask + scale + row max
            float tmax[4];
            #pragma unroll
            for (int r = 0; r < 4; ++r) tmax[r] = -1e30f;
            const int irow_base = q0 + w * 16 + ((lane >> 4) << 2);
            #pragma unroll
            for (int nf = 0; nf < 4; ++nf) {
                #pragma unroll
                for (int r = 0; r < 4; ++r) {
                    int i = irow_base + r;
                    int j = k0 + nf * 16 + (lane & 15);
                    float sv = s[nf][r] * scale;
                    bool ok = (j <= i) && (i - j < WINDOW);
                    sv = ok ? sv : -1e30f;
                    s[nf][r] = sv;
                    tmax[r] = fmaxf(tmax[r], sv);
                }
            }
            #pragma unroll
            for (int off = 1; off < 16; off <<= 1) {
                #pragma unroll
                for (int r = 0; r < 4; ++r)
                    tmax[r] = fmaxf(tmax[r], __shfl_xor(tmax[r], off, 64));
            }
            float mnew[4], sc[4], tsum[4];
            #pragma unroll
            for (int r = 0; r < 4; ++r) {
                mnew[r] = fmaxf(mrun[r], tmax[r]);
                sc[r] = __expf(mrun[r] - mnew[r]);
                mrun[r] = mnew[r];
                tsum[r] = 0.f;
            }
            // P = exp(S - m), write to per-wave LDS region
            #pragma unroll
            for (int nf = 0; nf < 4; ++nf) {
                #pragma unroll
                for (int r = 0; r < 4; ++r) {
                    float sv = s[nf][r];
                    float p = (sv > -1e29f) ? __expf(sv - mnew[r]) : 0.f;
                    tsum[r] += p;
                    Pl[w][((lane >> 4) << 2) + r][nf * 16 + (lane & 15)] = f2bf(p);
                }
            }
            #pragma unroll
            for (int off = 1; off < 16; off <<= 1) {
                #pragma unroll
                for (int r = 0; r < 4; ++r)
                    tsum[r] += __shfl_xor(tsum[r], off, 64);
            }
            #pragma unroll
            for (int r = 0; r < 4; ++r)
                lrun[r] = lrun[r] * sc[r] + tsum[r];
            #pragma unroll
            for (int nf = 0; nf < 4; ++nf)
                #pragma unroll
                for (int r = 0; r < 4; ++r)
                    o[nf][r] *= sc[r];

            // PV: O += P @ V
            bf16x8 pa0 = ld_bf8(&Pl[w][lane & 15][(lane >> 4) * 8]);
            bf16x8 pa1 = ld_bf8(&Pl[w][lane & 15][32 + (lane >> 4) * 8]);
            #pragma unroll
            for (int nf = 0; nf < 4; ++nf) {
                bf16x8 vb0 = ld_bf8(&Vl[nf * 16 + (lane & 15)][(lane >> 4) * 8]);
                bf16x8 vb1 = ld_bf8(&Vl[nf * 16 + (lane & 15)][32 + (lane >> 4) * 8]);
                o[nf] = __builtin_amdgcn_mfma_f32_16x16x32_bf16(pa0, vb0, o[nf], 0, 0, 0);
                o[nf] = __builtin_amdgcn_mfma_f32_16x16x32_bf16(pa1, vb1, o[nf], 0, 0, 0);
            }
        }
        __syncthreads();
    }

    // epilogue: O /= l, write to attn-out (B,T,H*D) bf16
    float inv[4];
    #pragma unroll
    for (int r = 0; r < 4; ++r) inv[r] = 1.f / lrun[r];
    #pragma unroll
    for (int nf = 0; nf < 4; ++nf) {
        #pragma unroll
        for (int r = 0; r < 4; ++r) {
            int i = q0 + w * 16 + ((lane >> 4) << 2) + r;
            int d = nf * 16 + (lane & 15);
            AO[((size_t)b * 2048 + i) * 2048 + h * 64 + d] = f2bf(o[nf][r] * inv[r]);
        }
    }
}

// ---------------- Output projection: out[4096 x 2048] = AO_bf16 @ Wo ----------------
__global__ __launch_bounds__(256)
void out_gemm(const u16* __restrict__ A, const float* __restrict__ Wo, float* __restrict__ C)
{
    const int K = 2048;
    __shared__ __align__(16) u16 Al[128][40];
    __shared__ __align__(16) u16 Bl[128][40];
    const int tid = threadIdx.x;
    const int lane = tid & 63;
    const int w = tid >> 6;
    const int wm = w >> 1, wn = w & 1;
    const int m0 = blockIdx.x * 128;
    const int n0 = blockIdx.y * 128;

    f32x4 acc[4][4] = {};

    const int ar = tid >> 1;
    const int ak = (tid & 1) * 16;
    const int bn = tid & 127;
    const int bk0 = (tid >> 7) * 16;

    for (int kb = 0; kb < K; kb += 32) {
        {
            const u16* ag = A + (size_t)(m0 + ar) * K + kb + ak;
            *(ushort8*)&Al[ar][ak]     = *(const ushort8*)ag;
            *(ushort8*)&Al[ar][ak + 8] = *(const ushort8*)(ag + 8);
        }
        {
            const float* bg = Wo + (size_t)(kb + bk0) * 2048 + n0 + bn;
            #pragma unroll
            for (int i = 0; i < 16; ++i) {
                Bl[bn][bk0 + i] = f2bf(bg[(size_t)i * 2048]);
            }
        }
        __syncthreads();

        bf16x8 af[4], bfr[4];
        #pragma unroll
        for (int m = 0; m < 4; ++m)
            af[m] = ld_bf8(&Al[wm * 64 + m * 16 + (lane & 15)][(lane >> 4) * 8]);
        #pragma unroll
        for (int n = 0; n < 4; ++n)
            bfr[n] = ld_bf8(&Bl[wn * 64 + n * 16 + (lane & 15)][(lane >> 4) * 8]);
        #pragma unroll
        for (int m = 0; m < 4; ++m)
            #pragma unroll
            for (int n = 0; n < 4; ++n)
                acc[m][n] = __builtin_amdgcn_mfma_f32_16x16x32_bf16(af[m], bfr[n], acc[m][n], 0, 0, 0);
        __syncthreads();
    }

    const int r0 = (lane >> 4) * 4;
    const int c0 = lane & 15;
    #pragma unroll
    for (int m = 0; m < 4; ++m) {
        #pragma unroll
        for (int n = 0; n < 4; ++n) {
            #pragma unroll
            for (int r = 0; r < 4; ++r) {
                int row = m0 + wm * 64 + m * 16 + r0 + r;
                int col = n0 + wn * 64 + n * 16 + c0;
                C[(size_t)row * 2048 + col] = acc[m][n][r];
            }
        }
    }
}

extern "C" void kernel_launch(void* const* d_in, const int* in_sizes, int n_in,
                              void* d_out, int out_size, void* d_ws, size_t ws_size,
                              hipStream_t stream)
{
    const float* x  = (const float*)d_in[0];
    const float* Wq = (const float*)d_in[1];
    const float* Wk = (const float*)d_in[2];
    const float* Wv = (const float*)d_in[3];
    const float* Wo = (const float*)d_in[4];
    float* out = (float*)d_out;

    u16* Qb = (u16*)d_ws;                               // 2*32*2048*64 = 8,388,608
    u16* Kb = Qb + (size_t)2 * 32 * 2048 * 64;          // 2*8*2048*64  = 2,097,152
    u16* Vb = Kb + (size_t)2 * 8 * 2048 * 64;
    u16* AO = Vb + (size_t)2 * 8 * 2048 * 64;           // 8,388,608

    qkv_gemm<<<dim3(32, 24), 256, 0, stream>>>(x, Wq, Wk, Wv, Qb, Kb, Vb);
    rope_kernel<<<(4194304 + 1048576) / 256, 256, 0, stream>>>(Qb, Kb);
    attn_kernel<<<dim3(32, 64), 256, 0, stream>>>(Qb, Kb, Vb, AO);
    out_gemm<<<dim3(32, 16), 256, 0, stream>>>(AO, Wo, out);
}